// Round 1
// baseline (478.410 us; speedup 1.0000x reference)
//
#include <hip/hip_runtime.h>

// Problem constants (match reference)
#define NO    20000
#define KC    11
#define DIM   256
#define NT    100000
#define OUT_F 128
#define KSEL  10

#define WAVES_PER_BLOCK 4
#define NBLOCKS (NO / WAVES_PER_BLOCK)   // 5000

// ---------------------------------------------------------------------------
// Kernel 1: w2[d] = sum_f W[d,f] * A[OUT_F + f],  d in [0, 2*DIM)
// ---------------------------------------------------------------------------
__global__ void compute_w2_kernel(const float* __restrict__ W,
                                  const float* __restrict__ A,
                                  float* __restrict__ w2) {
    int d = blockIdx.x * blockDim.x + threadIdx.x;
    if (d < 2 * DIM) {
        const float* wrow = W + (size_t)d * OUT_F;
        double a0 = 0.0, a1 = 0.0, a2 = 0.0, a3 = 0.0;
#pragma unroll 8
        for (int f = 0; f < OUT_F; f += 4) {
            a0 += (double)wrow[f + 0] * (double)A[OUT_F + f + 0];
            a1 += (double)wrow[f + 1] * (double)A[OUT_F + f + 1];
            a2 += (double)wrow[f + 2] * (double)A[OUT_F + f + 2];
            a3 += (double)wrow[f + 3] * (double)A[OUT_F + f + 3];
        }
        w2[d] = (float)((a0 + a1) + (a2 + a3));
    }
}

// ---------------------------------------------------------------------------
// Kernel 2: one wave per row n.
//
// R-prev post-mortem: VGPR_Count=64 showed the scheduler pressure-minimized
// and sank the 22 row loads into the consume loop (2-4 loads in flight /
// wave -> 2.9 TB/s, 46% of achievable, VALUBusy 11%). hbm_bytes was already
// ideal (433 MB), so the only lever is memory-level parallelism.
//
// This version forces issue-all-then-consume:
//   - lane-parallel ni/nd row load + __shfl broadcast (readlane -> SGPR
//     bases for the gathers; m-addresses wait on ONE load, not 11)
//   - sched_barrier(0) between load issue and consumption: the scheduler
//     may not sink any of the 22 float4 loads past it, so ~22 KB/wave is
//     in flight. Register peak ~150 fits the launch_bounds(256,3) cap
//     (~170) without spill; occupancy stays ~3 waves/SIMD.
// ---------------------------------------------------------------------------
__global__ __launch_bounds__(WAVES_PER_BLOCK * 64, 3)
void select_kernel(const float* __restrict__ Cand,
                   const float* __restrict__ nd_in,
                   const int*   __restrict__ ni_in,
                   const float* __restrict__ dtrain,
                   const float* __restrict__ w2,
                   float* __restrict__ outC,
                   float* __restrict__ outND,
                   float* __restrict__ outNI,
                   double* __restrict__ partA,
                   double* __restrict__ partB) {
    const int lane = threadIdx.x & 63;
    const int wv   = threadIdx.x >> 6;
    const int n    = blockIdx.x * WAVES_PER_BLOCK + wv;   // grid exactly covers NO

    // Per-lane slice of w2 (first 256 = candidate part, last 256 = dmc part)
    const float4 w2a = *(const float4*)(w2 + lane * 4);
    const float4 w2b = *(const float4*)(w2 + 256 + lane * 4);

    // 1) lane-parallel load of this row's neighbor ids + distances
    //    (1 load on the m-address critical path instead of 11)
    int   idx0 = 0;
    float ndv  = 0.f;
    if (lane < KC) {
        idx0 = ni_in[n * KC + lane];
        ndv  = nd_in[n * KC + lane];
    }

    // 2) all 11 candidate rows -> registers (independent of idx0; these
    //    loads fill the idx0 latency)
    const float* crow = Cand + ((size_t)n * KC) * DIM + lane * 4;
    float4 c[KC];
#pragma unroll
    for (int k = 0; k < KC; ++k)
        c[k] = *(const float4*)(crow + k * DIM);

    // 3) broadcast ids (readlane -> wave-uniform), issue all 11 gathers
    int inds[KC];
#pragma unroll
    for (int k = 0; k < KC; ++k)
        inds[k] = __shfl(idx0, k, 64);

    float4 m[KC];
#pragma unroll
    for (int k = 0; k < KC; ++k)
        m[k] = *(const float4*)(dtrain + (size_t)inds[k] * DIM + lane * 4);

    // Hard scheduling fence: all 22 row loads must be ISSUED before any
    // consumption is scheduled. This is what R-prev's launch_bounds alone
    // failed to achieve (scheduler sank loads to hit 64 VGPRs).
    __builtin_amdgcn_sched_barrier(0);

    // 4) per-lane partial scores (f64 for exact selection match) and row sums
    double e[KC];
    float  ps[KC];
    float  stp = 0.f;
#pragma unroll
    for (int k = 0; k < KC; ++k) {
        e[k] = (double)c[k].x * w2a.x + (double)c[k].y * w2a.y
             + (double)c[k].z * w2a.z + (double)c[k].w * w2a.w
             + (double)m[k].x * w2b.x + (double)m[k].y * w2b.y
             + (double)m[k].z * w2b.z + (double)m[k].w * w2b.w;
        ps[k] = (m[k].x + m[k].y) + (m[k].z + m[k].w);
        stp  += ps[k];
    }

    // 5) stage-major butterfly: 11 independent chains overlap per stage
#pragma unroll
    for (int off = 32; off; off >>= 1) {
#pragma unroll
        for (int k = 0; k < KC; ++k)
            e[k] += __shfl_xor(e[k], off, 64);
    }

    // 6) argmin with "drop the last tied index" (top_k keeps lower index on ties)
    double mine = e[0];
    int    drop = 0;
#pragma unroll
    for (int k = 1; k < KC; ++k)
        if (e[k] <= mine) { mine = e[k]; drop = k; }

    // 7) only 2 sum reductions needed: total and the dropped row
    float sd = ps[0];
#pragma unroll
    for (int k = 1; k < KC; ++k)
        sd = (drop == k) ? ps[k] : sd;
#pragma unroll
    for (int off = 32; off; off >>= 1) {
        stp += __shfl_xor(stp, off, 64);
        sd  += __shfl_xor(sd,  off, 64);
    }

    // 8) write the 10 surviving candidate rows (static register selects)
    const size_t ob = (size_t)n * KSEL * DIM + lane * 4;
#pragma unroll
    for (int j = 0; j < KSEL; ++j) {
        const float4 v = (j >= drop) ? c[j + 1] : c[j];
        *(float4*)(outC + ob + (size_t)j * DIM) = v;
    }

    // nd / ni epilogue via shuffle from the prefetched row (no late loads).
    // All 64 lanes run the shuffle (src clamped) so source lanes are active;
    // only lanes < KSEL store.
    {
        const int src = min(lane + (lane >= drop ? 1 : 0), KC - 1);
        const float ndo = __shfl(ndv, src, 64);
        const int   nio = __shfl(idx0, src, 64);
        if (lane < KSEL) {
            outND[n * KSEL + lane] = ndo;
            outNI[n * KSEL + lane] = (float)nio;   // exact for values < 2^24
        }
    }

    // Deterministic per-block partial sums for a_out / b_out
    __shared__ float shA[WAVES_PER_BLOCK], shB[WAVES_PER_BLOCK];
    if (lane == 0) { shA[wv] = stp - sd; shB[wv] = sd; }
    __syncthreads();
    if (threadIdx.x == 0) {
        float a = 0.f, b = 0.f;
#pragma unroll
        for (int w = 0; w < WAVES_PER_BLOCK; ++w) { a += shA[w]; b += shB[w]; }
        partA[blockIdx.x] = (double)a;
        partB[blockIdx.x] = (double)b;
    }
}

// ---------------------------------------------------------------------------
// Kernel 3: reduce the 5000 block partials -> a_out, b_out
// ---------------------------------------------------------------------------
__global__ void finalize_kernel(const double* __restrict__ partA,
                                const double* __restrict__ partB,
                                float* __restrict__ outA,
                                float* __restrict__ outB) {
    __shared__ double sA[256], sB[256];
    double a = 0.0, b = 0.0;
    for (int i = threadIdx.x; i < NBLOCKS; i += 256) {
        a += partA[i];
        b += partB[i];
    }
    sA[threadIdx.x] = a;
    sB[threadIdx.x] = b;
    __syncthreads();
    for (int s = 128; s; s >>= 1) {
        if (threadIdx.x < s) {
            sA[threadIdx.x] += sA[threadIdx.x + s];
            sB[threadIdx.x] += sB[threadIdx.x + s];
        }
        __syncthreads();
    }
    if (threadIdx.x == 0) {
        *outA = (float)(sA[0] / (double)((size_t)NO * KSEL));
        *outB = (float)(sB[0] / (double)NO);
    }
}

extern "C" void kernel_launch(void* const* d_in, const int* in_sizes, int n_in,
                              void* d_out, int out_size, void* d_ws, size_t ws_size,
                              hipStream_t stream) {
    // Input order: X, Candidate, neigh_dist, neigh_ind, data_m_train,
    //              data_m_batch, test, W, A
    const float* Cand   = (const float*)d_in[1];
    const float* ndist  = (const float*)d_in[2];
    const int*   nind   = (const int*)d_in[3];
    const float* dtrain = (const float*)d_in[4];
    const float* W      = (const float*)d_in[7];
    const float* A      = (const float*)d_in[8];

    float* out   = (float*)d_out;
    float* outC  = out;                                   // [NO, KSEL, DIM]
    float* outND = out + (size_t)NO * KSEL * DIM;         // [NO, KSEL]
    float* outNI = outND + (size_t)NO * KSEL;             // [NO, KSEL] (as f32)
    float* outA  = outNI + (size_t)NO * KSEL;             // scalar
    float* outB  = outA + 1;                              // scalar

    // Workspace layout: w2 (512 f32) @0, block partials (2 x 5000 f64) @4096
    float*  w2    = (float*)d_ws;
    double* partA = (double*)((char*)d_ws + 4096);
    double* partB = partA + NBLOCKS;

    compute_w2_kernel<<<2, 256, 0, stream>>>(W, A, w2);
    select_kernel<<<NBLOCKS, WAVES_PER_BLOCK * 64, 0, stream>>>(
        Cand, ndist, nind, dtrain, w2, outC, outND, outNI, partA, partB);
    finalize_kernel<<<1, 256, 0, stream>>>(partA, partB, outA, outB);
}

// Round 2
// 463.514 us; speedup vs baseline: 1.0321x; 1.0321x over previous
//
#include <hip/hip_runtime.h>

// Problem constants (match reference)
#define NO    20000
#define KC    11
#define DIM   256
#define NT    100000
#define OUT_F 128
#define KSEL  10

#define WAVES_PER_BLOCK 4
#define NBLOCKS (NO / WAVES_PER_BLOCK)   // 5000
#define GS_BLOCKS (NT / WAVES_PER_BLOCK) // 25000

// ---------------------------------------------------------------------------
// Kernel 1: w2[d] = sum_f W[d,f] * A[OUT_F + f],  d in [0, 2*DIM)
// ---------------------------------------------------------------------------
__global__ void compute_w2_kernel(const float* __restrict__ W,
                                  const float* __restrict__ A,
                                  float* __restrict__ w2) {
    int d = blockIdx.x * blockDim.x + threadIdx.x;
    if (d < 2 * DIM) {
        const float* wrow = W + (size_t)d * OUT_F;
        double a0 = 0.0, a1 = 0.0, a2 = 0.0, a3 = 0.0;
#pragma unroll 8
        for (int f = 0; f < OUT_F; f += 4) {
            a0 += (double)wrow[f + 0] * (double)A[OUT_F + f + 0];
            a1 += (double)wrow[f + 1] * (double)A[OUT_F + f + 1];
            a2 += (double)wrow[f + 2] * (double)A[OUT_F + f + 2];
            a3 += (double)wrow[f + 3] * (double)A[OUT_F + f + 3];
        }
        w2[d] = (float)((a0 + a1) + (a2 + a3));
    }
}

// ---------------------------------------------------------------------------
// Kernel 1b (NEW): per-training-row scalars.
//   g[t] = dot(dtrain[t], w2[256:512])   (f64, selection-exact)
//   s[t] = sum(dtrain[t])                (f32, SAME butterfly order as the
//                                         previous passing kernel's sd)
// The gathered dmc rows never reach the output — they contribute only via
// these two dot products. Precomputing them converts select_kernel's 225 MB
// random 1KB-gather stream (the latency/L3 bottleneck, invisible in
// FETCH_SIZE) into 220000 x 12B lookups from a 1.2 MB L2-resident table.
// ---------------------------------------------------------------------------
__global__ __launch_bounds__(WAVES_PER_BLOCK * 64)
void precompute_gs_kernel(const float* __restrict__ dtrain,
                          const float* __restrict__ w2,
                          double* __restrict__ gtab,
                          float*  __restrict__ stab) {
    const int lane = threadIdx.x & 63;
    const int wv   = threadIdx.x >> 6;
    const int t    = blockIdx.x * WAVES_PER_BLOCK + wv;   // grid covers NT exactly

    const float4 w2b = *(const float4*)(w2 + 256 + lane * 4);
    const float4 m   = *(const float4*)(dtrain + (size_t)t * DIM + lane * 4);

    double g = (double)m.x * w2b.x + (double)m.y * w2b.y
             + (double)m.z * w2b.z + (double)m.w * w2b.w;
    float  s = (m.x + m.y) + (m.z + m.w);

#pragma unroll
    for (int off = 32; off; off >>= 1) {
        g += __shfl_xor(g, off, 64);
        s += __shfl_xor(s, off, 64);
    }
    if (lane == 0) {
        gtab[t] = g;
        stab[t] = s;
    }
}

// ---------------------------------------------------------------------------
// Kernel 2: one wave per row n. Pure streaming now: read 11 candidate rows
// (11 KB), f64 dot + butterfly, write 10 rows (10 KB). All neighbor-table
// access is wave-uniform scalar-sized (ni/nd rows + 11 {g,s} lookups).
// ---------------------------------------------------------------------------
__global__ __launch_bounds__(WAVES_PER_BLOCK * 64, 4)
void select_kernel(const float* __restrict__ Cand,
                   const float* __restrict__ nd_in,
                   const int*   __restrict__ ni_in,
                   const double* __restrict__ gtab,
                   const float*  __restrict__ stab,
                   const float* __restrict__ w2,
                   float* __restrict__ outC,
                   float* __restrict__ outND,
                   float* __restrict__ outNI,
                   double* __restrict__ partA,
                   double* __restrict__ partB) {
    const int lane = threadIdx.x & 63;
    const int wv   = threadIdx.x >> 6;
    const int n    = blockIdx.x * WAVES_PER_BLOCK + wv;   // grid exactly covers NO

    const float4 w2a = *(const float4*)(w2 + lane * 4);

    // 1) candidate rows -> registers (the streaming payload; issue first)
    const float* crow = Cand + ((size_t)n * KC) * DIM + lane * 4;
    float4 c[KC];
#pragma unroll
    for (int k = 0; k < KC; ++k)
        c[k] = *(const float4*)(crow + k * DIM);

    // 2) wave-uniform neighbor metadata (scalar-load path; no VGPR cost)
    int inds[KC];
    float ndr[KC];
#pragma unroll
    for (int k = 0; k < KC; ++k) {
        inds[k] = ni_in[n * KC + k];
        ndr[k]  = nd_in[n * KC + k];
    }
    double g[KC];
    float  s[KC];
#pragma unroll
    for (int k = 0; k < KC; ++k) {
        g[k] = gtab[inds[k]];
        s[k] = stab[inds[k]];
    }

    // 3) per-lane f64 partial of the candidate part of the score
    double e[KC];
#pragma unroll
    for (int k = 0; k < KC; ++k) {
        e[k] = (double)c[k].x * w2a.x + (double)c[k].y * w2a.y
             + (double)c[k].z * w2a.z + (double)c[k].w * w2a.w;
    }

    // 4) stage-major butterfly: 11 independent chains overlap per stage
#pragma unroll
    for (int off = 32; off; off >>= 1) {
#pragma unroll
        for (int k = 0; k < KC; ++k)
            e[k] += __shfl_xor(e[k], off, 64);
    }

    // 5) add the (uniform) precomputed dmc part
#pragma unroll
    for (int k = 0; k < KC; ++k)
        e[k] += g[k];

    // 6) argmin with "drop the last tied index" (top_k keeps lower index on ties)
    double mine = e[0];
    int    drop = 0;
#pragma unroll
    for (int k = 1; k < KC; ++k)
        if (e[k] <= mine) { mine = e[k]; drop = k; }

    // 7) row sums from the precomputed per-row scalars (uniform, no reduce)
    double stot = 0.0;
#pragma unroll
    for (int k = 0; k < KC; ++k)
        stot += (double)s[k];
    double sd = (double)s[0];
#pragma unroll
    for (int k = 1; k < KC; ++k)
        sd = (drop == k) ? (double)s[k] : sd;

    // 8) write the 10 surviving candidate rows (static register selects)
    const size_t ob = (size_t)n * KSEL * DIM + lane * 4;
#pragma unroll
    for (int j = 0; j < KSEL; ++j) {
        const float4 v = (j >= drop) ? c[j + 1] : c[j];
        *(float4*)(outC + ob + (size_t)j * DIM) = v;
    }

    // nd / ni epilogue from the uniform scalar rows (cndmask chain, no loads)
    if (lane < KSEL) {
        const int src = lane + (lane >= drop ? 1 : 0);
        float ndo = ndr[0];
        int   nio = inds[0];
#pragma unroll
        for (int k = 1; k < KC; ++k) {
            ndo = (src == k) ? ndr[k]  : ndo;
            nio = (src == k) ? inds[k] : nio;
        }
        outND[n * KSEL + lane] = ndo;
        outNI[n * KSEL + lane] = (float)nio;   // exact for values < 2^24
    }

    // Deterministic per-block partial sums for a_out / b_out
    __shared__ double shA[WAVES_PER_BLOCK], shB[WAVES_PER_BLOCK];
    if (lane == 0) { shA[wv] = stot - sd; shB[wv] = sd; }
    __syncthreads();
    if (threadIdx.x == 0) {
        double a = 0.0, b = 0.0;
#pragma unroll
        for (int w = 0; w < WAVES_PER_BLOCK; ++w) { a += shA[w]; b += shB[w]; }
        partA[blockIdx.x] = a;
        partB[blockIdx.x] = b;
    }
}

// ---------------------------------------------------------------------------
// Kernel 3: reduce the 5000 block partials -> a_out, b_out
// ---------------------------------------------------------------------------
__global__ void finalize_kernel(const double* __restrict__ partA,
                                const double* __restrict__ partB,
                                float* __restrict__ outA,
                                float* __restrict__ outB) {
    __shared__ double sA[1024], sB[1024];
    double a = 0.0, b = 0.0;
    for (int i = threadIdx.x; i < NBLOCKS; i += 1024) {
        a += partA[i];
        b += partB[i];
    }
    sA[threadIdx.x] = a;
    sB[threadIdx.x] = b;
    __syncthreads();
    for (int s = 512; s; s >>= 1) {
        if (threadIdx.x < s) {
            sA[threadIdx.x] += sA[threadIdx.x + s];
            sB[threadIdx.x] += sB[threadIdx.x + s];
        }
        __syncthreads();
    }
    if (threadIdx.x == 0) {
        *outA = (float)(sA[0] / (double)((size_t)NO * KSEL));
        *outB = (float)(sB[0] / (double)NO);
    }
}

extern "C" void kernel_launch(void* const* d_in, const int* in_sizes, int n_in,
                              void* d_out, int out_size, void* d_ws, size_t ws_size,
                              hipStream_t stream) {
    // Input order: X, Candidate, neigh_dist, neigh_ind, data_m_train,
    //              data_m_batch, test, W, A
    const float* Cand   = (const float*)d_in[1];
    const float* ndist  = (const float*)d_in[2];
    const int*   nind   = (const int*)d_in[3];
    const float* dtrain = (const float*)d_in[4];
    const float* W      = (const float*)d_in[7];
    const float* A      = (const float*)d_in[8];

    float* out   = (float*)d_out;
    float* outC  = out;                                   // [NO, KSEL, DIM]
    float* outND = out + (size_t)NO * KSEL * DIM;         // [NO, KSEL]
    float* outNI = outND + (size_t)NO * KSEL;             // [NO, KSEL] (as f32)
    float* outA  = outNI + (size_t)NO * KSEL;             // scalar
    float* outB  = outA + 1;                              // scalar

    // Workspace layout:
    //   w2 (512 f32)                @ 0
    //   partA/partB (2 x 5000 f64)  @ 4096
    //   gtab (NT f64)               @ 128 KiB     (800 KB)
    //   stab (NT f32)               @ 128 KiB + 800 KB (400 KB) -> ~1.33 MB total
    float*  w2    = (float*)d_ws;
    double* partA = (double*)((char*)d_ws + 4096);
    double* partB = partA + NBLOCKS;
    double* gtab  = (double*)((char*)d_ws + (1 << 17));
    float*  stab  = (float*)((char*)d_ws + (1 << 17) + (size_t)NT * sizeof(double));

    compute_w2_kernel<<<2, 256, 0, stream>>>(W, A, w2);
    precompute_gs_kernel<<<GS_BLOCKS, WAVES_PER_BLOCK * 64, 0, stream>>>(
        dtrain, w2, gtab, stab);
    select_kernel<<<NBLOCKS, WAVES_PER_BLOCK * 64, 0, stream>>>(
        Cand, ndist, nind, gtab, stab, w2, outC, outND, outNI, partA, partB);
    finalize_kernel<<<1, 1024, 0, stream>>>(partA, partB, outA, outB);
}